// Round 1
// baseline (2579.554 us; speedup 1.0000x reference)
//
#include <hip/hip_runtime.h>
#include <cstdint>
#include <cstddef>

#define HW     16384      // H*W
#define WIDTH  128
#define NB     2
#define NTOPK  300
#define JUNC_TH 0.008f

// ---------------------------------------------------------------- utilities
__device__ __forceinline__ unsigned long long shfl_xor_u64(unsigned long long v, int m) {
  int lo = (int)(unsigned)(v & 0xffffffffull);
  int hi = (int)(unsigned)(v >> 32);
  lo = __shfl_xor(lo, m, 64);
  hi = __shfl_xor(hi, m, 64);
  return ((unsigned long long)(unsigned)hi << 32) | (unsigned)lo;
}

__device__ __forceinline__ float sigm(float x) { return 1.0f / (1.0f + expf(-x)); }

// ---------------------------------------------------------------- W transpose (256x128 <- 128x256)
__global__ void k_transpose_w(const float* __restrict__ w, float* __restrict__ wt) {
  int i = blockIdx.x * 256 + threadIdx.x;   // 32768
  int d = i & 127, c = i >> 7;
  wt[c * 128 + d] = w[d * 256 + c];
}

// ---------------------------------------------------------------- loi GEMM: loi_t[b][p][d] = sum_c F[b][c][p]*W[d][c] + bias[d]
// BM=64 pixels, BN=128 d (all), BK=8. 256 threads, 4m x 8n per thread.
__global__ __launch_bounds__(256) void k_loi(const float* __restrict__ F,
                                             const float* __restrict__ wt,
                                             const float* __restrict__ bias,
                                             float* __restrict__ loi) {
  int b = blockIdx.y;
  int p0 = blockIdx.x * 64;
  __shared__ float As[8][64];
  __shared__ float Bs[8][128];
  int t = threadIdx.x;
  int tn = t & 15;    // n group: n = tn*8
  int tm = t >> 4;    // m group: m = tm*4
  float acc[4][8];
#pragma unroll
  for (int i = 0; i < 4; ++i)
#pragma unroll
    for (int j = 0; j < 8; ++j) acc[i][j] = 0.0f;

  const float* Fb = F + (size_t)b * 256 * HW;
  for (int c0 = 0; c0 < 256; c0 += 8) {
    __syncthreads();
    if (t < 128) {
      int kk = t >> 4, mv = t & 15;
      float4 v = *(const float4*)(Fb + (size_t)(c0 + kk) * HW + p0 + mv * 4);
      *(float4*)&As[kk][mv * 4] = v;
    }
    {
      int kk = t >> 5, dv = t & 31;
      float4 v = *(const float4*)(wt + (size_t)(c0 + kk) * 128 + dv * 4);
      *(float4*)&Bs[kk][dv * 4] = v;
    }
    __syncthreads();
#pragma unroll
    for (int kk = 0; kk < 8; ++kk) {
      float4 a4 = *(const float4*)&As[kk][tm * 4];
      float4 b0 = *(const float4*)&Bs[kk][tn * 8];
      float4 b1 = *(const float4*)&Bs[kk][tn * 8 + 4];
      float av[4] = {a4.x, a4.y, a4.z, a4.w};
      float bv[8] = {b0.x, b0.y, b0.z, b0.w, b1.x, b1.y, b1.z, b1.w};
#pragma unroll
      for (int i = 0; i < 4; ++i)
#pragma unroll
        for (int j = 0; j < 8; ++j) acc[i][j] += av[i] * bv[j];
    }
  }
  float4 c0v = *(const float4*)(bias + tn * 8);
  float4 c1v = *(const float4*)(bias + tn * 8 + 4);
  float bb[8] = {c0v.x, c0v.y, c0v.z, c0v.w, c1v.x, c1v.y, c1v.z, c1v.w};
#pragma unroll
  for (int i = 0; i < 4; ++i) {
    int p = p0 + tm * 4 + i;
    float* dst = loi + ((size_t)b * HW + p) * 128 + tn * 8;
    float4 o0 = make_float4(acc[i][0] + bb[0], acc[i][1] + bb[1], acc[i][2] + bb[2], acc[i][3] + bb[3]);
    float4 o1 = make_float4(acc[i][4] + bb[4], acc[i][5] + bb[5], acc[i][6] + bb[6], acc[i][7] + bb[7]);
    *(float4*)dst = o0;
    *(float4*)(dst + 4) = o1;
  }
}

// ---------------------------------------------------------------- jloc = softmax(out9[5:7])[1]
__global__ void k_jloc(const float* __restrict__ out9, float* __restrict__ jloc) {
  int i = blockIdx.x * 256 + threadIdx.x;    // NB*HW
  int b = i >> 14, p = i & (HW - 1);
  const float* base = out9 + (size_t)b * 9 * HW;
  float o5 = base[5 * HW + p], o6 = base[6 * HW + p];
  float m = fmaxf(o5, o6);
  float e5 = expf(o5 - m), e6 = expf(o6 - m);
  jloc[i] = e6 / (e5 + e6);
}

// ---------------------------------------------------------------- NMS + sortable key
__global__ void k_nmskey(const float* __restrict__ jloc, unsigned long long* __restrict__ keys) {
  int i = blockIdx.x * 256 + threadIdx.x;
  int b = i >> 14, p = i & (HW - 1);
  int y = p >> 7, x = p & 127;
  const float* J = jloc + (size_t)b * HW;
  float c = J[p];
  float m = c;
  for (int dy = -1; dy <= 1; ++dy) {
    int yy = y + dy;
    if (yy < 0 || yy > 127) continue;
    for (int dx = -1; dx <= 1; ++dx) {
      int xx = x + dx;
      if (xx < 0 || xx > 127) continue;
      m = fmaxf(m, J[yy * WIDTH + xx]);
    }
  }
  unsigned int vb = (c == m) ? __float_as_uint(c) : 0u;   // jloc > 0 always -> bits monotone
  keys[i] = ((unsigned long long)vb << 32) | (unsigned int)(~p);
}

// ---------------------------------------------------------------- top-300 per image (1 block/image)
__global__ __launch_bounds__(1024) void k_topk(const unsigned long long* __restrict__ keys,
                                               const float* __restrict__ out9,
                                               float* __restrict__ jx, float* __restrict__ jy) {
  int b = blockIdx.x;
  __shared__ unsigned long long cand[4608];
  __shared__ unsigned long long wmax[16];
  __shared__ unsigned long long bestk;
  __shared__ int cnt;
  int t = threadIdx.x;
  if (t == 0) cnt = 0;
  __syncthreads();
  const unsigned long long* K = keys + (size_t)b * HW;
  for (int i = t; i < HW; i += 1024) {
    unsigned long long k = K[i];
    if ((k >> 32) != 0ull) {
      int pos = atomicAdd(&cnt, 1);
      if (pos < 4608) cand[pos] = k;
    }
  }
  __syncthreads();
  int n = cnt < 4608 ? cnt : 4608;
  const float* o7 = out9 + (size_t)b * 9 * HW + 7 * HW;
  const float* o8 = out9 + (size_t)b * 9 * HW + 8 * HW;
  int lane = t & 63, wid = t >> 6;
  for (int r = 0; r < NTOPK; ++r) {
    unsigned long long best = 0ull;
    for (int j = t; j < n; j += 1024) {
      unsigned long long v = cand[j];
      if (v > best) best = v;
    }
#pragma unroll
    for (int off = 32; off > 0; off >>= 1) {
      unsigned long long o = shfl_xor_u64(best, off);
      if (o > best) best = o;
    }
    if (lane == 0) wmax[wid] = best;
    __syncthreads();
    if (t == 0) {
      unsigned long long bb = wmax[0];
      for (int w = 1; w < 16; ++w)
        if (wmax[w] > bb) bb = wmax[w];
      bestk = bb;
      unsigned int vb = (unsigned int)(bb >> 32);
      float val = __uint_as_float(vb);
      if (vb != 0u && val > JUNC_TH) {
        int p = (int)(~((unsigned int)(bb & 0xffffffffull))) & (HW - 1);
        float ox = sigm(o7[p]) - 0.5f;
        float oy = sigm(o8[p]) - 0.5f;
        jx[b * NTOPK + r] = (float)(p & 127) + ox + 0.5f;
        jy[b * NTOPK + r] = (float)(p >> 7) + oy + 0.5f;
      } else {
        jx[b * NTOPK + r] = 1000000.0f;
        jy[b * NTOPK + r] = 1000000.0f;
      }
    }
    __syncthreads();
    unsigned long long bb = bestk;
    for (int j = t; j < n; j += 1024)
      if (cand[j] == bb) cand[j] = 0ull;
    __syncthreads();
  }
}

// ---------------------------------------------------------------- per-line argmin assignment + lines2 output
__global__ __launch_bounds__(256) void k_lines(const float* __restrict__ lp,
                                               const float* __restrict__ jx,
                                               const float* __restrict__ jy,
                                               float4* __restrict__ lines4,
                                               int* __restrict__ iskeep,
                                               float* __restrict__ out_lines) {
  int b = blockIdx.y;
  int l = blockIdx.x * 256 + threadIdx.x;
  __shared__ float jxs[NTOPK], jys[NTOPK];
  for (int i = threadIdx.x; i < NTOPK; i += 256) {
    jxs[i] = jx[b * NTOPK + i];
    jys[i] = jy[b * NTOPK + i];
  }
  __syncthreads();
  int gl = b * HW + l;
  const float* L = lp + (size_t)gl * 4;
  float x1 = L[0], y1 = L[1], x2 = L[2], y2 = L[3];
  float bd1 = 3.4e38f, bd2 = 3.4e38f;
  int i1 = 0, i2 = 0;
  for (int j = 0; j < NTOPK; ++j) {
    float ax = __fsub_rn(x1, jxs[j]);
    float ay = __fsub_rn(y1, jys[j]);
    float d1 = __fadd_rn(__fmul_rn(ax, ax), __fmul_rn(ay, ay));
    if (d1 < bd1) { bd1 = d1; i1 = j; }
    float ex = __fsub_rn(x2, jxs[j]);
    float ey = __fsub_rn(y2, jys[j]);
    float d2 = __fadd_rn(__fmul_rn(ex, ex), __fmul_rn(ey, ey));
    if (d2 < bd2) { bd2 = d2; i2 = j; }
  }
  int imin = min(i1, i2), imax = max(i1, i2);
  float sx1 = jxs[imin], sy1 = jys[imin], sx2 = jxs[imax], sy2 = jys[imax];
  lines4[gl] = make_float4(sx1, sy1, sx2, sy2);
  iskeep[gl] = (imin < imax) ? 1 : 0;
  ((float4*)out_lines)[gl] = make_float4(sx1 * 4.0f, sy1 * 4.0f, sx2 * 4.0f, sy2 * 4.0f);
}

// ---------------------------------------------------------------- bilinear sample + maxpool -> xvec[l][c*8+g]
__global__ __launch_bounds__(128) void k_sample(const float* __restrict__ loi,
                                                const float4* __restrict__ lines4,
                                                float* __restrict__ xvec,
                                                int b, int l0) {
  int l = l0 + blockIdx.x;
  int gl = b * HW + l;
  int c = threadIdx.x;
  __shared__ float xrow[1024];
  float4 ln = lines4[gl];          // (start.x, start.y, end.x, end.y)
  const float* Lb = loi + (size_t)b * HW * 128;
  float runm = -3.4e38f;
#pragma unroll 4
  for (int k = 0; k < 32; ++k) {
    float t = (float)k * (1.0f / 31.0f);
    float tc = 1.0f - t;
    float px = ln.x * t + ln.z * tc - 0.5f;
    float py = ln.y * t + ln.w * tc - 0.5f;
    float px0 = fminf(fmaxf(floorf(px), 0.0f), 127.0f);
    float py0 = fminf(fmaxf(floorf(py), 0.0f), 127.0f);
    float px1 = fminf(px0 + 1.0f, 127.0f);
    float py1 = fminf(py0 + 1.0f, 127.0f);
    int ix0 = (int)px0, iy0 = (int)py0, ix1 = (int)px1, iy1 = (int)py1;
    float wy1 = __fsub_rn(py1, py), wy0 = __fsub_rn(py, py0);
    float wx1 = __fsub_rn(px1, px), wx0 = __fsub_rn(px, px0);
    float wa = __fmul_rn(wy1, wx1), wb = __fmul_rn(wy0, wx1);
    float wc = __fmul_rn(wy1, wx0), wd = __fmul_rn(wy0, wx0);
    const float* r00 = Lb + (size_t)(iy0 * WIDTH + ix0) * 128;
    const float* r10 = Lb + (size_t)(iy1 * WIDTH + ix0) * 128;
    const float* r01 = Lb + (size_t)(iy0 * WIDTH + ix1) * 128;
    const float* r11 = Lb + (size_t)(iy1 * WIDTH + ix1) * 128;
    // reference order: g00*wa + g10*wb + g01*wc + g11*wd (left-assoc, no fma)
    float v = __fadd_rn(__fadd_rn(__fadd_rn(__fmul_rn(r00[c], wa),
                                            __fmul_rn(r10[c], wb)),
                                  __fmul_rn(r01[c], wc)),
                        __fmul_rn(r11[c], wd));
    runm = fmaxf(runm, v);
    if ((k & 3) == 3) {
      xrow[c * 8 + (k >> 2)] = runm;
      runm = -3.4e38f;
    }
  }
  __syncthreads();
  const float4* s4 = (const float4*)xrow;
  float4* d4 = (float4*)(xvec + (size_t)(l - l0) * 1024);
  d4[c] = s4[c];
  d4[c + 128] = s4[c + 128];
}

// ---------------------------------------------------------------- FC GEMM: C = relu(A[M,1024] @ Bw[1024,1024] + bias)
// BM=128, BN=64, BK=16, 256 threads, 8m x 4n per thread.
__global__ __launch_bounds__(256) void k_gemm_relu(const float* __restrict__ A,
                                                   const float* __restrict__ Bw,
                                                   const float* __restrict__ bias,
                                                   float* __restrict__ C) {
  const int Kd = 1024, Nd = 1024;
  int m0 = blockIdx.x * 128, n0 = blockIdx.y * 64;
  __shared__ float As[16][128];
  __shared__ float Bs[16][64];
  int t = threadIdx.x;
  int tm = t >> 4;    // m = tm*8
  int tn = t & 15;    // n = tn*4
  float acc[8][4];
#pragma unroll
  for (int i = 0; i < 8; ++i)
#pragma unroll
    for (int j = 0; j < 4; ++j) acc[i][j] = 0.0f;

  for (int k0 = 0; k0 < Kd; k0 += 16) {
    __syncthreads();
#pragma unroll
    for (int r = 0; r < 2; ++r) {
      int e = t + r * 256;
      int m = e >> 2, kv = (e & 3) * 4;
      float4 v = *(const float4*)(A + (size_t)(m0 + m) * Kd + k0 + kv);
      As[kv + 0][m] = v.x;
      As[kv + 1][m] = v.y;
      As[kv + 2][m] = v.z;
      As[kv + 3][m] = v.w;
    }
    {
      int kk = t >> 4, nv = (t & 15) * 4;
      float4 v = *(const float4*)(Bw + (size_t)(k0 + kk) * Nd + n0 + nv);
      *(float4*)&Bs[kk][nv] = v;
    }
    __syncthreads();
#pragma unroll
    for (int kk = 0; kk < 16; ++kk) {
      float4 a0 = *(const float4*)&As[kk][tm * 8];
      float4 a1 = *(const float4*)&As[kk][tm * 8 + 4];
      float4 b4 = *(const float4*)&Bs[kk][tn * 4];
      float av[8] = {a0.x, a0.y, a0.z, a0.w, a1.x, a1.y, a1.z, a1.w};
      float bv[4] = {b4.x, b4.y, b4.z, b4.w};
#pragma unroll
      for (int i = 0; i < 8; ++i)
#pragma unroll
        for (int j = 0; j < 4; ++j) acc[i][j] += av[i] * bv[j];
    }
  }
  float4 bi = *(const float4*)(bias + n0 + tn * 4);
#pragma unroll
  for (int i = 0; i < 8; ++i) {
    int m = m0 + tm * 8 + i;
    float4 o = make_float4(fmaxf(acc[i][0] + bi.x, 0.0f),
                           fmaxf(acc[i][1] + bi.y, 0.0f),
                           fmaxf(acc[i][2] + bi.z, 0.0f),
                           fmaxf(acc[i][3] + bi.w, 0.0f));
    *(float4*)(C + (size_t)m * Nd + n0 + tn * 4) = o;
  }
}

// ---------------------------------------------------------------- logits + sigmoid + keep (1 wave per line)
__global__ __launch_bounds__(256) void k_logits(const float* __restrict__ h2,
                                                const float* __restrict__ w3,
                                                const float* __restrict__ b3,
                                                const int* __restrict__ iskeep,
                                                float* __restrict__ oscore,
                                                float* __restrict__ okeep,
                                                int b, int l0) {
  int wid = threadIdx.x >> 6, lane = threadIdx.x & 63;
  int lloc = blockIdx.x * 4 + wid;
  int gl = b * HW + l0 + lloc;
  const float* row = h2 + (size_t)lloc * 1024;
  float s = 0.0f;
  for (int f = lane; f < 1024; f += 64) s += row[f] * w3[f];
#pragma unroll
  for (int off = 32; off > 0; off >>= 1) s += __shfl_xor(s, off, 64);
  if (lane == 0) {
    float logit = s + b3[0];
    float sc = sigm(logit);
    oscore[gl] = sc;
    okeep[gl] = (iskeep[gl] && sc > 0.05f) ? 1.0f : 0.0f;
  }
}

// ================================================================ host
extern "C" void kernel_launch(void* const* d_in, const int* in_sizes, int n_in,
                              void* d_out, int out_size, void* d_ws, size_t ws_size,
                              hipStream_t stream) {
  const float* output     = (const float*)d_in[0];
  const float* features   = (const float*)d_in[1];
  const float* line_preds = (const float*)d_in[2];
  const float* conv_w     = (const float*)d_in[3];
  const float* conv_b     = (const float*)d_in[4];
  const float* w1         = (const float*)d_in[5];
  const float* b1         = (const float*)d_in[6];
  const float* w2         = (const float*)d_in[7];
  const float* b2         = (const float*)d_in[8];
  const float* w3         = (const float*)d_in[9];
  const float* b3         = (const float*)d_in[10];

  char* ws = (char*)d_ws;
  size_t off = 0;
  auto alloc = [&](size_t bytes) -> void* {
    void* p = ws + off;
    off += (bytes + 255) & ~(size_t)255;
    return p;
  };
  float* wt      = (float*)alloc((size_t)256 * 128 * 4);
  float* loi     = (float*)alloc((size_t)NB * HW * 128 * 4);
  float* jloc    = (float*)alloc((size_t)NB * HW * 4);
  unsigned long long* keys = (unsigned long long*)alloc((size_t)NB * HW * 8);
  float* jx      = (float*)alloc((size_t)NB * NTOPK * 4);
  float* jy      = (float*)alloc((size_t)NB * NTOPK * 4);
  float4* lines4 = (float4*)alloc((size_t)NB * HW * 16);
  int* iskeep    = (int*)alloc((size_t)NB * HW * 4);
  size_t fixed = off;

  // adaptive chunk: activations are 2 * CH * 1024 * 4 bytes
  int CH = 128;
  const int cands[8] = {16384, 8192, 4096, 2048, 1024, 512, 256, 128};
  for (int ci = 0; ci < 8; ++ci) {
    if (fixed + (size_t)2 * cands[ci] * 1024 * 4 + 512 <= ws_size) { CH = cands[ci]; break; }
  }
  float* xvec = (float*)alloc((size_t)CH * 1024 * 4);
  float* h1   = (float*)alloc((size_t)CH * 1024 * 4);
  float* h2   = xvec;   // alias: xvec dead after fc1

  float* out_lines  = (float*)d_out;              // (B, L, 2, 2)
  float* out_scores = out_lines + (size_t)NB * HW * 4;
  float* out_keep   = out_scores + (size_t)NB * HW;

  k_transpose_w<<<128, 256, 0, stream>>>(conv_w, wt);
  k_loi<<<dim3(HW / 64, NB), 256, 0, stream>>>(features, wt, conv_b, loi);
  k_jloc<<<NB * HW / 256, 256, 0, stream>>>(output, jloc);
  k_nmskey<<<NB * HW / 256, 256, 0, stream>>>(jloc, keys);
  k_topk<<<NB, 1024, 0, stream>>>(keys, output, jx, jy);
  k_lines<<<dim3(HW / 256, NB), 256, 0, stream>>>(line_preds, jx, jy, lines4, iskeep, out_lines);

  int nchunk = HW / CH;
  for (int b = 0; b < NB; ++b) {
    for (int ci = 0; ci < nchunk; ++ci) {
      int l0 = ci * CH;
      k_sample<<<CH, 128, 0, stream>>>(loi, lines4, xvec, b, l0);
      k_gemm_relu<<<dim3(CH / 128, 16), 256, 0, stream>>>(xvec, w1, b1, h1);
      k_gemm_relu<<<dim3(CH / 128, 16), 256, 0, stream>>>(h1, w2, b2, h2);
      k_logits<<<CH / 4, 256, 0, stream>>>(h2, w3, b3, iskeep, out_scores, out_keep, b, l0);
    }
  }
}

// Round 2
// 706.459 us; speedup vs baseline: 3.6514x; 3.6514x over previous
//
#include <hip/hip_runtime.h>
#include <hip/hip_bf16.h>
#include <cstdint>
#include <cstddef>

#define HW     16384      // H*W
#define WIDTH  128
#define NB     2
#define NTOPK  300
#define JUNC_TH 0.008f

typedef __attribute__((ext_vector_type(8))) short s16x8;
typedef __attribute__((ext_vector_type(4))) float f32x4;

// ---------------------------------------------------------------- utilities
__device__ __forceinline__ float sigm(float x) { return 1.0f / (1.0f + expf(-x)); }

__device__ __forceinline__ unsigned short f2bf(float f) {
  __hip_bfloat16 h = __float2bfloat16(f);
  return __hip_bfloat16_raw(h).x;
}
__device__ __forceinline__ float bf2f(unsigned short u) {
  __hip_bfloat16_raw r; r.x = u;
  return __bfloat162float(__hip_bfloat16(r));
}

#define GLOAD_LDS16(gp, lp)                                                        \
  __builtin_amdgcn_global_load_lds((const __attribute__((address_space(1))) void*)(gp), \
                                   (__attribute__((address_space(3))) void*)(lp), 16, 0, 0)

// ---------------------------------------------------------------- W transpose (256x128 <- 128x256), fp32
__global__ void k_transpose_w(const float* __restrict__ w, float* __restrict__ wt) {
  int i = blockIdx.x * 256 + threadIdx.x;   // 32768
  int d = i & 127, c = i >> 7;
  wt[c * 128 + d] = w[d * 256 + c];
}

// ---------------------------------------------------------------- FC weight transpose+cast: wt_bf16[n][k] = w[k][n]
__global__ __launch_bounds__(256) void k_wtrans(const float* __restrict__ w,
                                                unsigned short* __restrict__ wt) {
  __shared__ float tile[32][33];
  int n0 = blockIdx.x * 32, k0 = blockIdx.y * 32;
  int tx = threadIdx.x & 31, ty = threadIdx.x >> 5;   // 32 x 8
#pragma unroll
  for (int r = 0; r < 32; r += 8)
    tile[ty + r][tx] = w[(size_t)(k0 + ty + r) * 1024 + n0 + tx];
  __syncthreads();
#pragma unroll
  for (int r = 0; r < 32; r += 8)
    wt[(size_t)(n0 + ty + r) * 1024 + k0 + tx] = f2bf(tile[tx][ty + r]);
}

// ---------------------------------------------------------------- loi GEMM (fp32): loi_t[b][p][d]
__global__ __launch_bounds__(256) void k_loi(const float* __restrict__ F,
                                             const float* __restrict__ wt,
                                             const float* __restrict__ bias,
                                             float* __restrict__ loi) {
  int b = blockIdx.y;
  int p0 = blockIdx.x * 64;
  __shared__ float As[8][64];
  __shared__ float Bs[8][128];
  int t = threadIdx.x;
  int tn = t & 15;    // n group: n = tn*8
  int tm = t >> 4;    // m group: m = tm*4
  float acc[4][8];
#pragma unroll
  for (int i = 0; i < 4; ++i)
#pragma unroll
    for (int j = 0; j < 8; ++j) acc[i][j] = 0.0f;

  const float* Fb = F + (size_t)b * 256 * HW;
  for (int c0 = 0; c0 < 256; c0 += 8) {
    __syncthreads();
    if (t < 128) {
      int kk = t >> 4, mv = t & 15;
      float4 v = *(const float4*)(Fb + (size_t)(c0 + kk) * HW + p0 + mv * 4);
      *(float4*)&As[kk][mv * 4] = v;
    }
    {
      int kk = t >> 5, dv = t & 31;
      float4 v = *(const float4*)(wt + (size_t)(c0 + kk) * 128 + dv * 4);
      *(float4*)&Bs[kk][dv * 4] = v;
    }
    __syncthreads();
#pragma unroll
    for (int kk = 0; kk < 8; ++kk) {
      float4 a4 = *(const float4*)&As[kk][tm * 4];
      float4 b0 = *(const float4*)&Bs[kk][tn * 8];
      float4 b1 = *(const float4*)&Bs[kk][tn * 8 + 4];
      float av[4] = {a4.x, a4.y, a4.z, a4.w};
      float bv[8] = {b0.x, b0.y, b0.z, b0.w, b1.x, b1.y, b1.z, b1.w};
#pragma unroll
      for (int i = 0; i < 4; ++i)
#pragma unroll
        for (int j = 0; j < 8; ++j) acc[i][j] += av[i] * bv[j];
    }
  }
  float4 c0v = *(const float4*)(bias + tn * 8);
  float4 c1v = *(const float4*)(bias + tn * 8 + 4);
  float bb[8] = {c0v.x, c0v.y, c0v.z, c0v.w, c1v.x, c1v.y, c1v.z, c1v.w};
#pragma unroll
  for (int i = 0; i < 4; ++i) {
    int p = p0 + tm * 4 + i;
    float* dst = loi + ((size_t)b * HW + p) * 128 + tn * 8;
    float4 o0 = make_float4(acc[i][0] + bb[0], acc[i][1] + bb[1], acc[i][2] + bb[2], acc[i][3] + bb[3]);
    float4 o1 = make_float4(acc[i][4] + bb[4], acc[i][5] + bb[5], acc[i][6] + bb[6], acc[i][7] + bb[7]);
    *(float4*)dst = o0;
    *(float4*)(dst + 4) = o1;
  }
}

// ---------------------------------------------------------------- jloc = softmax(out9[5:7])[1]
__global__ void k_jloc(const float* __restrict__ out9, float* __restrict__ jloc) {
  int i = blockIdx.x * 256 + threadIdx.x;    // NB*HW
  int b = i >> 14, p = i & (HW - 1);
  const float* base = out9 + (size_t)b * 9 * HW;
  float o5 = base[5 * HW + p], o6 = base[6 * HW + p];
  float m = fmaxf(o5, o6);
  float e5 = expf(o5 - m), e6 = expf(o6 - m);
  jloc[i] = e6 / (e5 + e6);
}

// ---------------------------------------------------------------- NMS + sortable key
__global__ void k_nmskey(const float* __restrict__ jloc, unsigned long long* __restrict__ keys) {
  int i = blockIdx.x * 256 + threadIdx.x;
  int b = i >> 14, p = i & (HW - 1);
  int y = p >> 7, x = p & 127;
  const float* J = jloc + (size_t)b * HW;
  float c = J[p];
  float m = c;
  for (int dy = -1; dy <= 1; ++dy) {
    int yy = y + dy;
    if (yy < 0 || yy > 127) continue;
    for (int dx = -1; dx <= 1; ++dx) {
      int xx = x + dx;
      if (xx < 0 || xx > 127) continue;
      m = fmaxf(m, J[yy * WIDTH + xx]);
    }
  }
  unsigned int vb = (c == m) ? __float_as_uint(c) : 0u;   // jloc > 0 always -> bits monotone
  keys[i] = ((unsigned long long)vb << 32) | (unsigned int)(~p);
}

// ---------------------------------------------------------------- top-300 per image via bitonic sort (1 block/image)
__global__ __launch_bounds__(1024) void k_topk(const unsigned long long* __restrict__ keys,
                                               const float* __restrict__ out9,
                                               float* __restrict__ jx, float* __restrict__ jy) {
  int b = blockIdx.x;
  __shared__ unsigned long long cand[4096];
  __shared__ int cnt;
  int t = threadIdx.x;
  if (t == 0) cnt = 0;
#pragma unroll
  for (int i = t; i < 4096; i += 1024) cand[i] = 0ull;
  __syncthreads();
  const unsigned long long* K = keys + (size_t)b * HW;
  for (int i = t; i < HW; i += 1024) {
    unsigned long long k = K[i];
    if ((k >> 32) != 0ull) {
      int pos = atomicAdd(&cnt, 1);
      if (pos < 4096) cand[pos] = k;
    }
  }
  __syncthreads();
  // bitonic sort, descending (keys distinct except zero-padding)
  for (int k = 2; k <= 4096; k <<= 1) {
    for (int j = k >> 1; j > 0; j >>= 1) {
#pragma unroll
      for (int idx = t; idx < 4096; idx += 1024) {
        int ixj = idx ^ j;
        if (ixj > idx) {
          unsigned long long a = cand[idx], c = cand[ixj];
          bool up = ((idx & k) == 0);
          if (up ? (a < c) : (a > c)) { cand[idx] = c; cand[ixj] = a; }
        }
      }
      __syncthreads();
    }
  }
  if (t < NTOPK) {
    const float* o7 = out9 + (size_t)b * 9 * HW + 7 * HW;
    const float* o8 = out9 + (size_t)b * 9 * HW + 8 * HW;
    unsigned long long bb = cand[t];
    unsigned int vb = (unsigned int)(bb >> 32);
    float val = __uint_as_float(vb);
    if (vb != 0u && val > JUNC_TH) {
      int p = (int)(~((unsigned int)(bb & 0xffffffffull))) & (HW - 1);
      float ox = sigm(o7[p]) - 0.5f;
      float oy = sigm(o8[p]) - 0.5f;
      jx[b * NTOPK + t] = (float)(p & 127) + ox + 0.5f;
      jy[b * NTOPK + t] = (float)(p >> 7) + oy + 0.5f;
    } else {
      jx[b * NTOPK + t] = 1000000.0f;
      jy[b * NTOPK + t] = 1000000.0f;
    }
  }
}

// ---------------------------------------------------------------- per-line argmin assignment + lines2 output
__global__ __launch_bounds__(256) void k_lines(const float* __restrict__ lp,
                                               const float* __restrict__ jx,
                                               const float* __restrict__ jy,
                                               float4* __restrict__ lines4,
                                               int* __restrict__ iskeep,
                                               float* __restrict__ out_lines) {
  int b = blockIdx.y;
  int l = blockIdx.x * 256 + threadIdx.x;
  __shared__ float jxs[NTOPK], jys[NTOPK];
  for (int i = threadIdx.x; i < NTOPK; i += 256) {
    jxs[i] = jx[b * NTOPK + i];
    jys[i] = jy[b * NTOPK + i];
  }
  __syncthreads();
  int gl = b * HW + l;
  const float* L = lp + (size_t)gl * 4;
  float x1 = L[0], y1 = L[1], x2 = L[2], y2 = L[3];
  float bd1 = 3.4e38f, bd2 = 3.4e38f;
  int i1 = 0, i2 = 0;
  for (int j = 0; j < NTOPK; ++j) {
    float ax = __fsub_rn(x1, jxs[j]);
    float ay = __fsub_rn(y1, jys[j]);
    float d1 = __fadd_rn(__fmul_rn(ax, ax), __fmul_rn(ay, ay));
    if (d1 < bd1) { bd1 = d1; i1 = j; }
    float ex = __fsub_rn(x2, jxs[j]);
    float ey = __fsub_rn(y2, jys[j]);
    float d2 = __fadd_rn(__fmul_rn(ex, ex), __fmul_rn(ey, ey));
    if (d2 < bd2) { bd2 = d2; i2 = j; }
  }
  int imin = min(i1, i2), imax = max(i1, i2);
  float sx1 = jxs[imin], sy1 = jys[imin], sx2 = jxs[imax], sy2 = jys[imax];
  lines4[gl] = make_float4(sx1, sy1, sx2, sy2);
  iskeep[gl] = (imin < imax) ? 1 : 0;
  ((float4*)out_lines)[gl] = make_float4(sx1 * 4.0f, sy1 * 4.0f, sx2 * 4.0f, sy2 * 4.0f);
}

// ---------------------------------------------------------------- bilinear sample + maxpool -> xvec bf16 [l][c*8+g]
__global__ __launch_bounds__(128) void k_sample(const float* __restrict__ loi,
                                                const float4* __restrict__ lines4,
                                                unsigned short* __restrict__ xvec,
                                                int b, int l0) {
  int l = l0 + blockIdx.x;
  int gl = b * HW + l;
  int c = threadIdx.x;
  float4 ln = lines4[gl];          // (start.x, start.y, end.x, end.y)
  const float* Lb = loi + (size_t)b * HW * 128;
  alignas(16) unsigned short outv[8];
  float runm = -3.4e38f;
#pragma unroll 4
  for (int k = 0; k < 32; ++k) {
    float t = (float)k * (1.0f / 31.0f);
    float tc = 1.0f - t;
    float px = ln.x * t + ln.z * tc - 0.5f;
    float py = ln.y * t + ln.w * tc - 0.5f;
    float px0 = fminf(fmaxf(floorf(px), 0.0f), 127.0f);
    float py0 = fminf(fmaxf(floorf(py), 0.0f), 127.0f);
    float px1 = fminf(px0 + 1.0f, 127.0f);
    float py1 = fminf(py0 + 1.0f, 127.0f);
    int ix0 = (int)px0, iy0 = (int)py0, ix1 = (int)px1, iy1 = (int)py1;
    float wy1 = __fsub_rn(py1, py), wy0 = __fsub_rn(py, py0);
    float wx1 = __fsub_rn(px1, px), wx0 = __fsub_rn(px, px0);
    float wa = __fmul_rn(wy1, wx1), wb = __fmul_rn(wy0, wx1);
    float wc = __fmul_rn(wy1, wx0), wd = __fmul_rn(wy0, wx0);
    const float* r00 = Lb + (size_t)(iy0 * WIDTH + ix0) * 128;
    const float* r10 = Lb + (size_t)(iy1 * WIDTH + ix0) * 128;
    const float* r01 = Lb + (size_t)(iy0 * WIDTH + ix1) * 128;
    const float* r11 = Lb + (size_t)(iy1 * WIDTH + ix1) * 128;
    // reference order: g00*wa + g10*wb + g01*wc + g11*wd (left-assoc, no fma)
    float v = __fadd_rn(__fadd_rn(__fadd_rn(__fmul_rn(r00[c], wa),
                                            __fmul_rn(r10[c], wb)),
                                  __fmul_rn(r01[c], wc)),
                        __fmul_rn(r11[c], wd));
    runm = fmaxf(runm, v);
    if ((k & 3) == 3) {
      outv[k >> 2] = f2bf(runm);
      runm = -3.4e38f;
    }
  }
  *(s16x8*)(xvec + (size_t)(l - l0) * 1024 + c * 8) = *(const s16x8*)outv;
}

// ---------------------------------------------------------------- bf16 MFMA FC: C = relu(A[M,1024] @ Bt[1024,1024]^T + bias)
// 128x128 tile, 4 waves each 64x64, BK=32, global_load_lds staging, fragment-order LDS.
__global__ __launch_bounds__(256) void k_fc_mfma(const unsigned short* __restrict__ A,
                                                 const unsigned short* __restrict__ Bt,
                                                 const float* __restrict__ bias,
                                                 unsigned short* __restrict__ C) {
  const int K = 1024, N = 1024;
  __shared__ short sm[8192];           // As: 8 tiles x 512, Bs: 8 tiles x 512 (bf16 elems)
  short* As = sm;
  short* Bs = sm + 4096;
  int t = threadIdx.x, lane = t & 63, w = t >> 6;
  int wm = w & 1, wn = w >> 1;
  int lr = lane & 15, ls = lane >> 4;  // row-in-tile, k-segment
  int m0 = blockIdx.x * 128, n0 = blockIdx.y * 128;

  f32x4 acc[4][4];
#pragma unroll
  for (int i = 0; i < 4; ++i)
#pragma unroll
    for (int j = 0; j < 4; ++j) acc[i][j] = (f32x4){0.f, 0.f, 0.f, 0.f};

  const unsigned short* ga0 = A + (size_t)(m0 + w * 16 + lr) * K + ls * 8;
  const unsigned short* ga1 = A + (size_t)(m0 + (w + 4) * 16 + lr) * K + ls * 8;
  const unsigned short* gb0 = Bt + (size_t)(n0 + w * 16 + lr) * K + ls * 8;
  const unsigned short* gb1 = Bt + (size_t)(n0 + (w + 4) * 16 + lr) * K + ls * 8;

  for (int k0 = 0; k0 < K; k0 += 32) {
    __syncthreads();
    GLOAD_LDS16(ga0 + k0, As + w * 512);
    GLOAD_LDS16(ga1 + k0, As + (w + 4) * 512);
    GLOAD_LDS16(gb0 + k0, Bs + w * 512);
    GLOAD_LDS16(gb1 + k0, Bs + (w + 4) * 512);
    __syncthreads();
    s16x8 af[4], bfr[4];
#pragma unroll
    for (int mi = 0; mi < 4; ++mi) af[mi] = *(const s16x8*)(As + (wm * 4 + mi) * 512 + lane * 8);
#pragma unroll
    for (int ni = 0; ni < 4; ++ni) bfr[ni] = *(const s16x8*)(Bs + (wn * 4 + ni) * 512 + lane * 8);
#pragma unroll
    for (int mi = 0; mi < 4; ++mi)
#pragma unroll
      for (int ni = 0; ni < 4; ++ni)
        acc[mi][ni] = __builtin_amdgcn_mfma_f32_16x16x32_bf16(af[mi], bfr[ni], acc[mi][ni], 0, 0, 0);
  }

#pragma unroll
  for (int ni = 0; ni < 4; ++ni) {
    int col = n0 + wn * 64 + ni * 16 + lr;
    float bv = bias[col];
#pragma unroll
    for (int mi = 0; mi < 4; ++mi) {
      int row = m0 + wm * 64 + mi * 16 + ls * 4;
#pragma unroll
      for (int r = 0; r < 4; ++r) {
        float v = fmaxf(acc[mi][ni][r] + bv, 0.0f);
        C[(size_t)(row + r) * N + col] = f2bf(v);
      }
    }
  }
}

// ---------------------------------------------------------------- logits + sigmoid + keep (1 wave per line)
__global__ __launch_bounds__(256) void k_logits(const unsigned short* __restrict__ h2,
                                                const float* __restrict__ w3,
                                                const float* __restrict__ b3,
                                                const int* __restrict__ iskeep,
                                                float* __restrict__ oscore,
                                                float* __restrict__ okeep,
                                                int b, int l0) {
  int wid = threadIdx.x >> 6, lane = threadIdx.x & 63;
  int lloc = blockIdx.x * 4 + wid;
  int gl = b * HW + l0 + lloc;
  const unsigned short* row = h2 + (size_t)lloc * 1024;
  float s = 0.0f;
  for (int f = lane; f < 1024; f += 64) s += bf2f(row[f]) * w3[f];
#pragma unroll
  for (int off = 32; off > 0; off >>= 1) s += __shfl_xor(s, off, 64);
  if (lane == 0) {
    float logit = s + b3[0];
    float sc = sigm(logit);
    oscore[gl] = sc;
    okeep[gl] = (iskeep[gl] && sc > 0.05f) ? 1.0f : 0.0f;
  }
}

// ================================================================ host
extern "C" void kernel_launch(void* const* d_in, const int* in_sizes, int n_in,
                              void* d_out, int out_size, void* d_ws, size_t ws_size,
                              hipStream_t stream) {
  const float* output     = (const float*)d_in[0];
  const float* features   = (const float*)d_in[1];
  const float* line_preds = (const float*)d_in[2];
  const float* conv_w     = (const float*)d_in[3];
  const float* conv_b     = (const float*)d_in[4];
  const float* w1         = (const float*)d_in[5];
  const float* b1         = (const float*)d_in[6];
  const float* w2         = (const float*)d_in[7];
  const float* b2         = (const float*)d_in[8];
  const float* w3         = (const float*)d_in[9];
  const float* b3         = (const float*)d_in[10];

  char* ws = (char*)d_ws;
  size_t off = 0;
  auto alloc = [&](size_t bytes) -> void* {
    void* p = ws + off;
    off += (bytes + 255) & ~(size_t)255;
    return p;
  };
  float* wt      = (float*)alloc((size_t)256 * 128 * 4);
  float* loi     = (float*)alloc((size_t)NB * HW * 128 * 4);
  float* jloc    = (float*)alloc((size_t)NB * HW * 4);
  unsigned long long* keys = (unsigned long long*)alloc((size_t)NB * HW * 8);
  float* jx      = (float*)alloc((size_t)NB * NTOPK * 4);
  float* jy      = (float*)alloc((size_t)NB * NTOPK * 4);
  float4* lines4 = (float4*)alloc((size_t)NB * HW * 16);
  int* iskeep    = (int*)alloc((size_t)NB * HW * 4);
  unsigned short* w1b = (unsigned short*)alloc((size_t)1024 * 1024 * 2);   // [N][K] bf16
  unsigned short* w2b = (unsigned short*)alloc((size_t)1024 * 1024 * 2);
  size_t fixed = off;

  // adaptive chunk: activations are 2 * CH * 1024 * 2 bytes (bf16)
  int CH = 128;
  const int cands[8] = {16384, 8192, 4096, 2048, 1024, 512, 256, 128};
  for (int ci = 0; ci < 8; ++ci) {
    if (fixed + (size_t)2 * cands[ci] * 1024 * 2 + 512 <= ws_size) { CH = cands[ci]; break; }
  }
  unsigned short* xvec = (unsigned short*)alloc((size_t)CH * 1024 * 2);
  unsigned short* h1   = (unsigned short*)alloc((size_t)CH * 1024 * 2);
  unsigned short* h2   = xvec;   // alias: xvec dead after fc1

  float* out_lines  = (float*)d_out;              // (B, L, 2, 2)
  float* out_scores = out_lines + (size_t)NB * HW * 4;
  float* out_keep   = out_scores + (size_t)NB * HW;

  k_transpose_w<<<128, 256, 0, stream>>>(conv_w, wt);
  k_wtrans<<<dim3(32, 32), 256, 0, stream>>>(w1, w1b);
  k_wtrans<<<dim3(32, 32), 256, 0, stream>>>(w2, w2b);
  k_loi<<<dim3(HW / 64, NB), 256, 0, stream>>>(features, wt, conv_b, loi);
  k_jloc<<<NB * HW / 256, 256, 0, stream>>>(output, jloc);
  k_nmskey<<<NB * HW / 256, 256, 0, stream>>>(jloc, keys);
  k_topk<<<NB, 1024, 0, stream>>>(keys, output, jx, jy);
  k_lines<<<dim3(HW / 256, NB), 256, 0, stream>>>(line_preds, jx, jy, lines4, iskeep, out_lines);

  int nchunk = HW / CH;
  for (int b = 0; b < NB; ++b) {
    for (int ci = 0; ci < nchunk; ++ci) {
      int l0 = ci * CH;
      k_sample<<<CH, 128, 0, stream>>>(loi, lines4, xvec, b, l0);
      k_fc_mfma<<<dim3(CH / 128, 8), 256, 0, stream>>>(xvec, w1b, b1, h1);
      k_fc_mfma<<<dim3(CH / 128, 8), 256, 0, stream>>>(h1, w2b, b2, h2);
      k_logits<<<CH / 4, 256, 0, stream>>>(h2, w3, b3, iskeep, out_scores, out_keep, b, l0);
    }
  }
}

// Round 3
// 608.379 us; speedup vs baseline: 4.2400x; 1.1612x over previous
//
#include <hip/hip_runtime.h>
#include <hip/hip_bf16.h>
#include <cstdint>
#include <cstddef>

#define HW     16384      // H*W
#define WIDTH  128
#define NB     2
#define NTOPK  300
#define JUNC_TH 0.008f

typedef __attribute__((ext_vector_type(8))) short s16x8;
typedef __attribute__((ext_vector_type(4))) float f32x4;

// ---------------------------------------------------------------- utilities
__device__ __forceinline__ float sigm(float x) { return 1.0f / (1.0f + expf(-x)); }

__device__ __forceinline__ unsigned short f2bf(float f) {
  __hip_bfloat16 h = __float2bfloat16(f);
  return __hip_bfloat16_raw(h).x;
}
__device__ __forceinline__ float bf2f(unsigned short u) {
  __hip_bfloat16_raw r; r.x = u;
  return __bfloat162float(__hip_bfloat16(r));
}
__device__ __forceinline__ float2 bf2x2(unsigned int u) {
  return make_float2(__uint_as_float(u << 16), __uint_as_float(u & 0xffff0000u));
}

#define GLOAD_LDS16(gp, lp)                                                        \
  __builtin_amdgcn_global_load_lds((const __attribute__((address_space(1))) void*)(gp), \
                                   (__attribute__((address_space(3))) void*)(lp), 16, 0, 0)

// ---------------------------------------------------------------- W transpose (256x128 <- 128x256), fp32
__global__ void k_transpose_w(const float* __restrict__ w, float* __restrict__ wt) {
  int i = blockIdx.x * 256 + threadIdx.x;   // 32768
  int d = i & 127, c = i >> 7;
  wt[c * 128 + d] = w[d * 256 + c];
}

// ---------------------------------------------------------------- FC weight transpose+cast: wt_bf16[n][k] = w[k][n]
__global__ __launch_bounds__(256) void k_wtrans(const float* __restrict__ w,
                                                unsigned short* __restrict__ wt) {
  __shared__ float tile[32][33];
  int n0 = blockIdx.x * 32, k0 = blockIdx.y * 32;
  int tx = threadIdx.x & 31, ty = threadIdx.x >> 5;   // 32 x 8
#pragma unroll
  for (int r = 0; r < 32; r += 8)
    tile[ty + r][tx] = w[(size_t)(k0 + ty + r) * 1024 + n0 + tx];
  __syncthreads();
#pragma unroll
  for (int r = 0; r < 32; r += 8)
    wt[(size_t)(n0 + ty + r) * 1024 + k0 + tx] = f2bf(tile[tx][ty + r]);
}

// ---------------------------------------------------------------- loi GEMM (fp32 math, bf16 store): loi_t[b][p][d]
__global__ __launch_bounds__(256) void k_loi(const float* __restrict__ F,
                                             const float* __restrict__ wt,
                                             const float* __restrict__ bias,
                                             unsigned short* __restrict__ loi) {
  int b = blockIdx.y;
  int p0 = blockIdx.x * 64;
  __shared__ float As[8][64];
  __shared__ float Bs[8][128];
  int t = threadIdx.x;
  int tn = t & 15;    // n group: n = tn*8
  int tm = t >> 4;    // m group: m = tm*4
  float acc[4][8];
#pragma unroll
  for (int i = 0; i < 4; ++i)
#pragma unroll
    for (int j = 0; j < 8; ++j) acc[i][j] = 0.0f;

  const float* Fb = F + (size_t)b * 256 * HW;
  for (int c0 = 0; c0 < 256; c0 += 8) {
    __syncthreads();
    if (t < 128) {
      int kk = t >> 4, mv = t & 15;
      float4 v = *(const float4*)(Fb + (size_t)(c0 + kk) * HW + p0 + mv * 4);
      *(float4*)&As[kk][mv * 4] = v;
    }
    {
      int kk = t >> 5, dv = t & 31;
      float4 v = *(const float4*)(wt + (size_t)(c0 + kk) * 128 + dv * 4);
      *(float4*)&Bs[kk][dv * 4] = v;
    }
    __syncthreads();
#pragma unroll
    for (int kk = 0; kk < 8; ++kk) {
      float4 a4 = *(const float4*)&As[kk][tm * 4];
      float4 b0 = *(const float4*)&Bs[kk][tn * 8];
      float4 b1 = *(const float4*)&Bs[kk][tn * 8 + 4];
      float av[4] = {a4.x, a4.y, a4.z, a4.w};
      float bv[8] = {b0.x, b0.y, b0.z, b0.w, b1.x, b1.y, b1.z, b1.w};
#pragma unroll
      for (int i = 0; i < 4; ++i)
#pragma unroll
        for (int j = 0; j < 8; ++j) acc[i][j] += av[i] * bv[j];
    }
  }
  float4 c0v = *(const float4*)(bias + tn * 8);
  float4 c1v = *(const float4*)(bias + tn * 8 + 4);
  float bb[8] = {c0v.x, c0v.y, c0v.z, c0v.w, c1v.x, c1v.y, c1v.z, c1v.w};
#pragma unroll
  for (int i = 0; i < 4; ++i) {
    int p = p0 + tm * 4 + i;
    alignas(16) unsigned short o[8];
#pragma unroll
    for (int j = 0; j < 8; ++j) o[j] = f2bf(acc[i][j] + bb[j]);
    *(s16x8*)(loi + ((size_t)b * HW + p) * 128 + tn * 8) = *(const s16x8*)o;
  }
}

// ---------------------------------------------------------------- jloc = softmax(out9[5:7])[1]
__global__ void k_jloc(const float* __restrict__ out9, float* __restrict__ jloc) {
  int i = blockIdx.x * 256 + threadIdx.x;    // NB*HW
  int b = i >> 14, p = i & (HW - 1);
  const float* base = out9 + (size_t)b * 9 * HW;
  float o5 = base[5 * HW + p], o6 = base[6 * HW + p];
  float m = fmaxf(o5, o6);
  float e5 = expf(o5 - m), e6 = expf(o6 - m);
  jloc[i] = e6 / (e5 + e6);
}

// ---------------------------------------------------------------- NMS + sortable key
__global__ void k_nmskey(const float* __restrict__ jloc, unsigned long long* __restrict__ keys) {
  int i = blockIdx.x * 256 + threadIdx.x;
  int b = i >> 14, p = i & (HW - 1);
  int y = p >> 7, x = p & 127;
  const float* J = jloc + (size_t)b * HW;
  float c = J[p];
  float m = c;
  for (int dy = -1; dy <= 1; ++dy) {
    int yy = y + dy;
    if (yy < 0 || yy > 127) continue;
    for (int dx = -1; dx <= 1; ++dx) {
      int xx = x + dx;
      if (xx < 0 || xx > 127) continue;
      m = fmaxf(m, J[yy * WIDTH + xx]);
    }
  }
  unsigned int vb = (c == m) ? __float_as_uint(c) : 0u;   // jloc > 0 always -> bits monotone
  keys[i] = ((unsigned long long)vb << 32) | (unsigned int)(~p);
}

// ---------------------------------------------------------------- top-300 per image via bitonic sort (1 block/image)
__global__ __launch_bounds__(1024) void k_topk(const unsigned long long* __restrict__ keys,
                                               const float* __restrict__ out9,
                                               float* __restrict__ jx, float* __restrict__ jy) {
  int b = blockIdx.x;
  __shared__ unsigned long long cand[4096];
  __shared__ int cnt;
  int t = threadIdx.x;
  if (t == 0) cnt = 0;
#pragma unroll
  for (int i = t; i < 4096; i += 1024) cand[i] = 0ull;
  __syncthreads();
  const unsigned long long* K = keys + (size_t)b * HW;
  for (int i = t; i < HW; i += 1024) {
    unsigned long long k = K[i];
    if ((k >> 32) != 0ull) {
      int pos = atomicAdd(&cnt, 1);
      if (pos < 4096) cand[pos] = k;
    }
  }
  __syncthreads();
  // bitonic sort, descending (keys distinct except zero-padding)
  for (int k = 2; k <= 4096; k <<= 1) {
    for (int j = k >> 1; j > 0; j >>= 1) {
#pragma unroll
      for (int idx = t; idx < 4096; idx += 1024) {
        int ixj = idx ^ j;
        if (ixj > idx) {
          unsigned long long a = cand[idx], c = cand[ixj];
          bool up = ((idx & k) == 0);
          if (up ? (a < c) : (a > c)) { cand[idx] = c; cand[ixj] = a; }
        }
      }
      __syncthreads();
    }
  }
  if (t < NTOPK) {
    const float* o7 = out9 + (size_t)b * 9 * HW + 7 * HW;
    const float* o8 = out9 + (size_t)b * 9 * HW + 8 * HW;
    unsigned long long bb = cand[t];
    unsigned int vb = (unsigned int)(bb >> 32);
    float val = __uint_as_float(vb);
    if (vb != 0u && val > JUNC_TH) {
      int p = (int)(~((unsigned int)(bb & 0xffffffffull))) & (HW - 1);
      float ox = sigm(o7[p]) - 0.5f;
      float oy = sigm(o8[p]) - 0.5f;
      jx[b * NTOPK + t] = (float)(p & 127) + ox + 0.5f;
      jy[b * NTOPK + t] = (float)(p >> 7) + oy + 0.5f;
    } else {
      jx[b * NTOPK + t] = 1000000.0f;
      jy[b * NTOPK + t] = 1000000.0f;
    }
  }
}

// ---------------------------------------------------------------- per-line argmin assignment + lines2 output
__global__ __launch_bounds__(256) void k_lines(const float* __restrict__ lp,
                                               const float* __restrict__ jx,
                                               const float* __restrict__ jy,
                                               float4* __restrict__ lines4,
                                               int* __restrict__ iskeep,
                                               float* __restrict__ out_lines) {
  int b = blockIdx.y;
  int l = blockIdx.x * 256 + threadIdx.x;
  __shared__ float jxs[NTOPK], jys[NTOPK];
  for (int i = threadIdx.x; i < NTOPK; i += 256) {
    jxs[i] = jx[b * NTOPK + i];
    jys[i] = jy[b * NTOPK + i];
  }
  __syncthreads();
  int gl = b * HW + l;
  const float* L = lp + (size_t)gl * 4;
  float x1 = L[0], y1 = L[1], x2 = L[2], y2 = L[3];
  float bd1 = 3.4e38f, bd2 = 3.4e38f;
  int i1 = 0, i2 = 0;
  for (int j = 0; j < NTOPK; ++j) {
    float ax = __fsub_rn(x1, jxs[j]);
    float ay = __fsub_rn(y1, jys[j]);
    float d1 = __fadd_rn(__fmul_rn(ax, ax), __fmul_rn(ay, ay));
    if (d1 < bd1) { bd1 = d1; i1 = j; }
    float ex = __fsub_rn(x2, jxs[j]);
    float ey = __fsub_rn(y2, jys[j]);
    float d2 = __fadd_rn(__fmul_rn(ex, ex), __fmul_rn(ey, ey));
    if (d2 < bd2) { bd2 = d2; i2 = j; }
  }
  int imin = min(i1, i2), imax = max(i1, i2);
  float sx1 = jxs[imin], sy1 = jys[imin], sx2 = jxs[imax], sy2 = jys[imax];
  lines4[gl] = make_float4(sx1, sy1, sx2, sy2);
  iskeep[gl] = (imin < imax) ? 1 : 0;
  ((float4*)out_lines)[gl] = make_float4(sx1 * 4.0f, sy1 * 4.0f, sx2 * 4.0f, sy2 * 4.0f);
}

// ---------------------------------------------------------------- bilinear sample + maxpool
// 2 lines per block, 128 threads: t>>6 = line-in-block, t&63 = channel pair.
// Geometry (offsets+weights) computed once by threads 0..63 into LDS.
__global__ __launch_bounds__(128) void k_sample(const unsigned short* __restrict__ loi,
                                                const float4* __restrict__ lines4,
                                                unsigned short* __restrict__ xvec,
                                                int b, int l0) {
  __shared__ int   soff[2][32][4];
  __shared__ float swt[2][32][4];
  int t = threadIdx.x;
  if (t < 64) {
    int li = t >> 5, k = t & 31;
    int l = l0 + blockIdx.x * 2 + li;
    float4 ln = lines4[b * HW + l];
    float tt = (float)k * (1.0f / 31.0f);
    float tc = 1.0f - tt;
    float px = ln.x * tt + ln.z * tc - 0.5f;
    float py = ln.y * tt + ln.w * tc - 0.5f;
    float px0 = fminf(fmaxf(floorf(px), 0.0f), 127.0f);
    float py0 = fminf(fmaxf(floorf(py), 0.0f), 127.0f);
    float px1 = fminf(px0 + 1.0f, 127.0f);
    float py1 = fminf(py0 + 1.0f, 127.0f);
    int ix0 = (int)px0, iy0 = (int)py0, ix1 = (int)px1, iy1 = (int)py1;
    float wy1 = __fsub_rn(py1, py), wy0 = __fsub_rn(py, py0);
    float wx1 = __fsub_rn(px1, px), wx0 = __fsub_rn(px, px0);
    soff[li][k][0] = (iy0 * WIDTH + ix0) * 128;
    soff[li][k][1] = (iy1 * WIDTH + ix0) * 128;
    soff[li][k][2] = (iy0 * WIDTH + ix1) * 128;
    soff[li][k][3] = (iy1 * WIDTH + ix1) * 128;
    swt[li][k][0] = __fmul_rn(wy1, wx1);   // wa -> r00
    swt[li][k][1] = __fmul_rn(wy0, wx1);   // wb -> r10
    swt[li][k][2] = __fmul_rn(wy1, wx0);   // wc -> r01
    swt[li][k][3] = __fmul_rn(wy0, wx0);   // wd -> r11
  }
  __syncthreads();
  int li = t >> 6, c2 = t & 63;            // channels 2*c2, 2*c2+1
  int l = l0 + blockIdx.x * 2 + li;
  const unsigned short* Lb = loi + (size_t)b * HW * 128 + (c2 << 1);
  float rm0 = -3.4e38f, rm1 = -3.4e38f;
  alignas(16) unsigned short outv[16];
#pragma unroll 4
  for (int k = 0; k < 32; ++k) {
    int4   o = *(const int4*)soff[li][k];
    float4 w = *(const float4*)swt[li][k];
    unsigned int u0 = *(const unsigned int*)(Lb + o.x);
    unsigned int u1 = *(const unsigned int*)(Lb + o.y);
    unsigned int u2 = *(const unsigned int*)(Lb + o.z);
    unsigned int u3 = *(const unsigned int*)(Lb + o.w);
    float2 v0 = bf2x2(u0), v1 = bf2x2(u1), v2 = bf2x2(u2), v3 = bf2x2(u3);
    // reference order: g00*wa + g10*wb + g01*wc + g11*wd (left-assoc, no fma)
    float a0 = __fadd_rn(__fadd_rn(__fadd_rn(__fmul_rn(v0.x, w.x), __fmul_rn(v1.x, w.y)),
                                   __fmul_rn(v2.x, w.z)), __fmul_rn(v3.x, w.w));
    float a1 = __fadd_rn(__fadd_rn(__fadd_rn(__fmul_rn(v0.y, w.x), __fmul_rn(v1.y, w.y)),
                                   __fmul_rn(v2.y, w.z)), __fmul_rn(v3.y, w.w));
    rm0 = fmaxf(rm0, a0);
    rm1 = fmaxf(rm1, a1);
    if ((k & 3) == 3) {
      outv[k >> 2]     = f2bf(rm0);
      outv[8 + (k >> 2)] = f2bf(rm1);
      rm0 = -3.4e38f; rm1 = -3.4e38f;
    }
  }
  unsigned short* dst = xvec + (size_t)(l - l0) * 1024 + c2 * 16;
  *(s16x8*)dst       = *(const s16x8*)outv;
  *(s16x8*)(dst + 8) = *(const s16x8*)(outv + 8);
}

// ---------------------------------------------------------------- bf16 MFMA FC: C = relu(A[M,1024] @ Bt[1024,1024]^T + bias)
// 128x128 tile, 4 waves each 64x64, BK=32, global_load_lds staging, fragment-order LDS.
__global__ __launch_bounds__(256) void k_fc_mfma(const unsigned short* __restrict__ A,
                                                 const unsigned short* __restrict__ Bt,
                                                 const float* __restrict__ bias,
                                                 unsigned short* __restrict__ C) {
  const int K = 1024, N = 1024;
  __shared__ short sm[8192];           // As: 8 tiles x 512, Bs: 8 tiles x 512 (bf16 elems)
  short* As = sm;
  short* Bs = sm + 4096;
  int t = threadIdx.x, lane = t & 63, w = t >> 6;
  int wm = w & 1, wn = w >> 1;
  int lr = lane & 15, ls = lane >> 4;  // row-in-tile, k-segment
  int m0 = blockIdx.x * 128, n0 = blockIdx.y * 128;

  f32x4 acc[4][4];
#pragma unroll
  for (int i = 0; i < 4; ++i)
#pragma unroll
    for (int j = 0; j < 4; ++j) acc[i][j] = (f32x4){0.f, 0.f, 0.f, 0.f};

  const unsigned short* ga0 = A + (size_t)(m0 + w * 16 + lr) * K + ls * 8;
  const unsigned short* ga1 = A + (size_t)(m0 + (w + 4) * 16 + lr) * K + ls * 8;
  const unsigned short* gb0 = Bt + (size_t)(n0 + w * 16 + lr) * K + ls * 8;
  const unsigned short* gb1 = Bt + (size_t)(n0 + (w + 4) * 16 + lr) * K + ls * 8;

  for (int k0 = 0; k0 < K; k0 += 32) {
    __syncthreads();
    GLOAD_LDS16(ga0 + k0, As + w * 512);
    GLOAD_LDS16(ga1 + k0, As + (w + 4) * 512);
    GLOAD_LDS16(gb0 + k0, Bs + w * 512);
    GLOAD_LDS16(gb1 + k0, Bs + (w + 4) * 512);
    __syncthreads();
    s16x8 af[4], bfr[4];
#pragma unroll
    for (int mi = 0; mi < 4; ++mi) af[mi] = *(const s16x8*)(As + (wm * 4 + mi) * 512 + lane * 8);
#pragma unroll
    for (int ni = 0; ni < 4; ++ni) bfr[ni] = *(const s16x8*)(Bs + (wn * 4 + ni) * 512 + lane * 8);
#pragma unroll
    for (int mi = 0; mi < 4; ++mi)
#pragma unroll
      for (int ni = 0; ni < 4; ++ni)
        acc[mi][ni] = __builtin_amdgcn_mfma_f32_16x16x32_bf16(af[mi], bfr[ni], acc[mi][ni], 0, 0, 0);
  }

#pragma unroll
  for (int ni = 0; ni < 4; ++ni) {
    int col = n0 + wn * 64 + ni * 16 + lr;
    float bv = bias[col];
#pragma unroll
    for (int mi = 0; mi < 4; ++mi) {
      int row = m0 + wm * 64 + mi * 16 + ls * 4;
#pragma unroll
      for (int r = 0; r < 4; ++r) {
        float v = fmaxf(acc[mi][ni][r] + bv, 0.0f);
        C[(size_t)(row + r) * N + col] = f2bf(v);
      }
    }
  }
}

// ---------------------------------------------------------------- logits + sigmoid + keep (1 wave per line)
__global__ __launch_bounds__(256) void k_logits(const unsigned short* __restrict__ h2,
                                                const float* __restrict__ w3,
                                                const float* __restrict__ b3,
                                                const int* __restrict__ iskeep,
                                                float* __restrict__ oscore,
                                                float* __restrict__ okeep,
                                                int b, int l0) {
  int wid = threadIdx.x >> 6, lane = threadIdx.x & 63;
  int lloc = blockIdx.x * 4 + wid;
  int gl = b * HW + l0 + lloc;
  const unsigned short* row = h2 + (size_t)lloc * 1024;
  float s = 0.0f;
  for (int f = lane; f < 1024; f += 64) s += bf2f(row[f]) * w3[f];
#pragma unroll
  for (int off = 32; off > 0; off >>= 1) s += __shfl_xor(s, off, 64);
  if (lane == 0) {
    float logit = s + b3[0];
    float sc = sigm(logit);
    oscore[gl] = sc;
    okeep[gl] = (iskeep[gl] && sc > 0.05f) ? 1.0f : 0.0f;
  }
}

// ================================================================ host
extern "C" void kernel_launch(void* const* d_in, const int* in_sizes, int n_in,
                              void* d_out, int out_size, void* d_ws, size_t ws_size,
                              hipStream_t stream) {
  const float* output     = (const float*)d_in[0];
  const float* features   = (const float*)d_in[1];
  const float* line_preds = (const float*)d_in[2];
  const float* conv_w     = (const float*)d_in[3];
  const float* conv_b     = (const float*)d_in[4];
  const float* w1         = (const float*)d_in[5];
  const float* b1         = (const float*)d_in[6];
  const float* w2         = (const float*)d_in[7];
  const float* b2         = (const float*)d_in[8];
  const float* w3         = (const float*)d_in[9];
  const float* b3         = (const float*)d_in[10];

  char* ws = (char*)d_ws;
  size_t off = 0;
  auto alloc = [&](size_t bytes) -> void* {
    void* p = ws + off;
    off += (bytes + 255) & ~(size_t)255;
    return p;
  };
  float* wt      = (float*)alloc((size_t)256 * 128 * 4);
  unsigned short* loi = (unsigned short*)alloc((size_t)NB * HW * 128 * 2);
  float* jloc    = (float*)alloc((size_t)NB * HW * 4);
  unsigned long long* keys = (unsigned long long*)alloc((size_t)NB * HW * 8);
  float* jx      = (float*)alloc((size_t)NB * NTOPK * 4);
  float* jy      = (float*)alloc((size_t)NB * NTOPK * 4);
  float4* lines4 = (float4*)alloc((size_t)NB * HW * 16);
  int* iskeep    = (int*)alloc((size_t)NB * HW * 4);
  unsigned short* w1b = (unsigned short*)alloc((size_t)1024 * 1024 * 2);   // [N][K] bf16
  unsigned short* w2b = (unsigned short*)alloc((size_t)1024 * 1024 * 2);
  size_t fixed = off;

  // adaptive chunk: activations are 2 * CH * 1024 * 2 bytes (bf16)
  int CH = 128;
  const int cands[8] = {16384, 8192, 4096, 2048, 1024, 512, 256, 128};
  for (int ci = 0; ci < 8; ++ci) {
    if (fixed + (size_t)2 * cands[ci] * 1024 * 2 + 512 <= ws_size) { CH = cands[ci]; break; }
  }
  unsigned short* xvec = (unsigned short*)alloc((size_t)CH * 1024 * 2);
  unsigned short* h1   = (unsigned short*)alloc((size_t)CH * 1024 * 2);
  unsigned short* h2   = xvec;   // alias: xvec dead after fc1

  float* out_lines  = (float*)d_out;              // (B, L, 2, 2)
  float* out_scores = out_lines + (size_t)NB * HW * 4;
  float* out_keep   = out_scores + (size_t)NB * HW;

  k_transpose_w<<<128, 256, 0, stream>>>(conv_w, wt);
  k_wtrans<<<dim3(32, 32), 256, 0, stream>>>(w1, w1b);
  k_wtrans<<<dim3(32, 32), 256, 0, stream>>>(w2, w2b);
  k_loi<<<dim3(HW / 64, NB), 256, 0, stream>>>(features, wt, conv_b, loi);
  k_jloc<<<NB * HW / 256, 256, 0, stream>>>(output, jloc);
  k_nmskey<<<NB * HW / 256, 256, 0, stream>>>(jloc, keys);
  k_topk<<<NB, 1024, 0, stream>>>(keys, output, jx, jy);
  k_lines<<<dim3(HW / 256, NB), 256, 0, stream>>>(line_preds, jx, jy, lines4, iskeep, out_lines);

  int nchunk = HW / CH;
  for (int b = 0; b < NB; ++b) {
    for (int ci = 0; ci < nchunk; ++ci) {
      int l0 = ci * CH;
      k_sample<<<CH / 2, 128, 0, stream>>>(loi, lines4, xvec, b, l0);
      k_fc_mfma<<<dim3(CH / 128, 8), 256, 0, stream>>>(xvec, w1b, b1, h1);
      k_fc_mfma<<<dim3(CH / 128, 8), 256, 0, stream>>>(h1, w2b, b2, h2);
      k_logits<<<CH / 4, 256, 0, stream>>>(h2, w3, b3, iskeep, out_scores, out_keep, b, l0);
    }
  }
}

// Round 4
// 535.000 us; speedup vs baseline: 4.8216x; 1.1372x over previous
//
#include <hip/hip_runtime.h>
#include <hip/hip_bf16.h>
#include <cstdint>
#include <cstddef>

#define HW     16384      // H*W
#define WIDTH  128
#define NB     2
#define NTOPK  300
#define JUNC_TH 0.008f

typedef __attribute__((ext_vector_type(8))) short s16x8;
typedef __attribute__((ext_vector_type(4))) float f32x4;

// ---------------------------------------------------------------- utilities
__device__ __forceinline__ float sigm(float x) { return 1.0f / (1.0f + expf(-x)); }

__device__ __forceinline__ unsigned short f2bf(float f) {
  __hip_bfloat16 h = __float2bfloat16(f);
  return __hip_bfloat16_raw(h).x;
}
__device__ __forceinline__ float bf2f(unsigned short u) {
  __hip_bfloat16_raw r; r.x = u;
  return __bfloat162float(__hip_bfloat16(r));
}
__device__ __forceinline__ float2 bf2x2(unsigned int u) {
  return make_float2(__uint_as_float(u << 16), __uint_as_float(u & 0xffff0000u));
}

#define GLOAD_LDS16(gp, lp)                                                        \
  __builtin_amdgcn_global_load_lds((const __attribute__((address_space(1))) void*)(gp), \
                                   (__attribute__((address_space(3))) void*)(lp), 16, 0, 0)

// ---------------------------------------------------------------- W transpose (256x128 <- 128x256), fp32
__global__ void k_transpose_w(const float* __restrict__ w, float* __restrict__ wt) {
  int i = blockIdx.x * 256 + threadIdx.x;   // 32768
  int d = i & 127, c = i >> 7;
  wt[c * 128 + d] = w[d * 256 + c];
}

// ---------------------------------------------------------------- FC weight transpose+cast: wt_bf16[n][k] = w[k][n]
__global__ __launch_bounds__(256) void k_wtrans(const float* __restrict__ w,
                                                unsigned short* __restrict__ wt) {
  __shared__ float tile[32][33];
  int n0 = blockIdx.x * 32, k0 = blockIdx.y * 32;
  int tx = threadIdx.x & 31, ty = threadIdx.x >> 5;   // 32 x 8
#pragma unroll
  for (int r = 0; r < 32; r += 8)
    tile[ty + r][tx] = w[(size_t)(k0 + ty + r) * 1024 + n0 + tx];
  __syncthreads();
#pragma unroll
  for (int r = 0; r < 32; r += 8)
    wt[(size_t)(n0 + ty + r) * 1024 + k0 + tx] = f2bf(tile[tx][ty + r]);
}

// ---------------------------------------------------------------- loi GEMM (fp32 math, bf16 store): loi_t[b][p][d]
__global__ __launch_bounds__(256) void k_loi(const float* __restrict__ F,
                                             const float* __restrict__ wt,
                                             const float* __restrict__ bias,
                                             unsigned short* __restrict__ loi) {
  int b = blockIdx.y;
  int p0 = blockIdx.x * 64;
  __shared__ float As[8][64];
  __shared__ float Bs[8][128];
  int t = threadIdx.x;
  int tn = t & 15;    // n group: n = tn*8
  int tm = t >> 4;    // m group: m = tm*4
  float acc[4][8];
#pragma unroll
  for (int i = 0; i < 4; ++i)
#pragma unroll
    for (int j = 0; j < 8; ++j) acc[i][j] = 0.0f;

  const float* Fb = F + (size_t)b * 256 * HW;
  for (int c0 = 0; c0 < 256; c0 += 8) {
    __syncthreads();
    if (t < 128) {
      int kk = t >> 4, mv = t & 15;
      float4 v = *(const float4*)(Fb + (size_t)(c0 + kk) * HW + p0 + mv * 4);
      *(float4*)&As[kk][mv * 4] = v;
    }
    {
      int kk = t >> 5, dv = t & 31;
      float4 v = *(const float4*)(wt + (size_t)(c0 + kk) * 128 + dv * 4);
      *(float4*)&Bs[kk][dv * 4] = v;
    }
    __syncthreads();
#pragma unroll
    for (int kk = 0; kk < 8; ++kk) {
      float4 a4 = *(const float4*)&As[kk][tm * 4];
      float4 b0 = *(const float4*)&Bs[kk][tn * 8];
      float4 b1 = *(const float4*)&Bs[kk][tn * 8 + 4];
      float av[4] = {a4.x, a4.y, a4.z, a4.w};
      float bv[8] = {b0.x, b0.y, b0.z, b0.w, b1.x, b1.y, b1.z, b1.w};
#pragma unroll
      for (int i = 0; i < 4; ++i)
#pragma unroll
        for (int j = 0; j < 8; ++j) acc[i][j] += av[i] * bv[j];
    }
  }
  float4 c0v = *(const float4*)(bias + tn * 8);
  float4 c1v = *(const float4*)(bias + tn * 8 + 4);
  float bb[8] = {c0v.x, c0v.y, c0v.z, c0v.w, c1v.x, c1v.y, c1v.z, c1v.w};
#pragma unroll
  for (int i = 0; i < 4; ++i) {
    int p = p0 + tm * 4 + i;
    alignas(16) unsigned short o[8];
#pragma unroll
    for (int j = 0; j < 8; ++j) o[j] = f2bf(acc[i][j] + bb[j]);
    *(s16x8*)(loi + ((size_t)b * HW + p) * 128 + tn * 8) = *(const s16x8*)o;
  }
}

// ---------------------------------------------------------------- jloc = softmax(out9[5:7])[1]
__global__ void k_jloc(const float* __restrict__ out9, float* __restrict__ jloc) {
  int i = blockIdx.x * 256 + threadIdx.x;    // NB*HW
  int b = i >> 14, p = i & (HW - 1);
  const float* base = out9 + (size_t)b * 9 * HW;
  float o5 = base[5 * HW + p], o6 = base[6 * HW + p];
  float m = fmaxf(o5, o6);
  float e5 = expf(o5 - m), e6 = expf(o6 - m);
  jloc[i] = e6 / (e5 + e6);
}

// ---------------------------------------------------------------- NMS + sortable key
__global__ void k_nmskey(const float* __restrict__ jloc, unsigned long long* __restrict__ keys) {
  int i = blockIdx.x * 256 + threadIdx.x;
  int b = i >> 14, p = i & (HW - 1);
  int y = p >> 7, x = p & 127;
  const float* J = jloc + (size_t)b * HW;
  float c = J[p];
  float m = c;
  for (int dy = -1; dy <= 1; ++dy) {
    int yy = y + dy;
    if (yy < 0 || yy > 127) continue;
    for (int dx = -1; dx <= 1; ++dx) {
      int xx = x + dx;
      if (xx < 0 || xx > 127) continue;
      m = fmaxf(m, J[yy * WIDTH + xx]);
    }
  }
  unsigned int vb = (c == m) ? __float_as_uint(c) : 0u;   // jloc > 0 always -> bits monotone
  keys[i] = ((unsigned long long)vb << 32) | (unsigned int)(~p);
}

// ---------------------------------------------------------------- top-300 per image via bitonic sort (1 block/image)
__global__ __launch_bounds__(1024) void k_topk(const unsigned long long* __restrict__ keys,
                                               const float* __restrict__ out9,
                                               float* __restrict__ jx, float* __restrict__ jy) {
  int b = blockIdx.x;
  __shared__ unsigned long long cand[4096];
  __shared__ int cnt;
  int t = threadIdx.x;
  if (t == 0) cnt = 0;
#pragma unroll
  for (int i = t; i < 4096; i += 1024) cand[i] = 0ull;
  __syncthreads();
  const unsigned long long* K = keys + (size_t)b * HW;
  for (int i = t; i < HW; i += 1024) {
    unsigned long long k = K[i];
    if ((k >> 32) != 0ull) {
      int pos = atomicAdd(&cnt, 1);
      if (pos < 4096) cand[pos] = k;
    }
  }
  __syncthreads();
  // bitonic sort, descending (keys distinct except zero-padding)
  for (int k = 2; k <= 4096; k <<= 1) {
    for (int j = k >> 1; j > 0; j >>= 1) {
#pragma unroll
      for (int idx = t; idx < 4096; idx += 1024) {
        int ixj = idx ^ j;
        if (ixj > idx) {
          unsigned long long a = cand[idx], c = cand[ixj];
          bool up = ((idx & k) == 0);
          if (up ? (a < c) : (a > c)) { cand[idx] = c; cand[ixj] = a; }
        }
      }
      __syncthreads();
    }
  }
  if (t < NTOPK) {
    const float* o7 = out9 + (size_t)b * 9 * HW + 7 * HW;
    const float* o8 = out9 + (size_t)b * 9 * HW + 8 * HW;
    unsigned long long bb = cand[t];
    unsigned int vb = (unsigned int)(bb >> 32);
    float val = __uint_as_float(vb);
    if (vb != 0u && val > JUNC_TH) {
      int p = (int)(~((unsigned int)(bb & 0xffffffffull))) & (HW - 1);
      float ox = sigm(o7[p]) - 0.5f;
      float oy = sigm(o8[p]) - 0.5f;
      jx[b * NTOPK + t] = (float)(p & 127) + ox + 0.5f;
      jy[b * NTOPK + t] = (float)(p >> 7) + oy + 0.5f;
    } else {
      jx[b * NTOPK + t] = 1000000.0f;
      jy[b * NTOPK + t] = 1000000.0f;
    }
  }
}

// ---------------------------------------------------------------- per-line argmin assignment + lines2 output (+ logits zero)
__global__ __launch_bounds__(256) void k_lines(const float* __restrict__ lp,
                                               const float* __restrict__ jx,
                                               const float* __restrict__ jy,
                                               float4* __restrict__ lines4,
                                               int* __restrict__ iskeep,
                                               float* __restrict__ out_lines,
                                               float* __restrict__ logits) {
  int b = blockIdx.y;
  int l = blockIdx.x * 256 + threadIdx.x;
  __shared__ float jxs[NTOPK], jys[NTOPK];
  for (int i = threadIdx.x; i < NTOPK; i += 256) {
    jxs[i] = jx[b * NTOPK + i];
    jys[i] = jy[b * NTOPK + i];
  }
  __syncthreads();
  int gl = b * HW + l;
  const float* L = lp + (size_t)gl * 4;
  float x1 = L[0], y1 = L[1], x2 = L[2], y2 = L[3];
  float bd1 = 3.4e38f, bd2 = 3.4e38f;
  int i1 = 0, i2 = 0;
  for (int j = 0; j < NTOPK; ++j) {
    float ax = __fsub_rn(x1, jxs[j]);
    float ay = __fsub_rn(y1, jys[j]);
    float d1 = __fadd_rn(__fmul_rn(ax, ax), __fmul_rn(ay, ay));
    if (d1 < bd1) { bd1 = d1; i1 = j; }
    float ex = __fsub_rn(x2, jxs[j]);
    float ey = __fsub_rn(y2, jys[j]);
    float d2 = __fadd_rn(__fmul_rn(ex, ex), __fmul_rn(ey, ey));
    if (d2 < bd2) { bd2 = d2; i2 = j; }
  }
  int imin = min(i1, i2), imax = max(i1, i2);
  float sx1 = jxs[imin], sy1 = jys[imin], sx2 = jxs[imax], sy2 = jys[imax];
  lines4[gl] = make_float4(sx1, sy1, sx2, sy2);
  iskeep[gl] = (imin < imax) ? 1 : 0;
  logits[gl] = 0.0f;
  ((float4*)out_lines)[gl] = make_float4(sx1 * 4.0f, sy1 * 4.0f, sx2 * 4.0f, sy2 * 4.0f);
}

// ---------------------------------------------------------------- bilinear sample + maxpool
// 2 lines per block, 128 threads: t>>6 = line-in-block, t&63 = channel pair.
__global__ __launch_bounds__(128) void k_sample(const unsigned short* __restrict__ loi,
                                                const float4* __restrict__ lines4,
                                                unsigned short* __restrict__ xvec,
                                                int b, int l0) {
  __shared__ int   soff[2][32][4];
  __shared__ float swt[2][32][4];
  int t = threadIdx.x;
  if (t < 64) {
    int li = t >> 5, k = t & 31;
    int l = l0 + blockIdx.x * 2 + li;
    float4 ln = lines4[b * HW + l];
    float tt = (float)k * (1.0f / 31.0f);
    float tc = 1.0f - tt;
    float px = ln.x * tt + ln.z * tc - 0.5f;
    float py = ln.y * tt + ln.w * tc - 0.5f;
    float px0 = fminf(fmaxf(floorf(px), 0.0f), 127.0f);
    float py0 = fminf(fmaxf(floorf(py), 0.0f), 127.0f);
    float px1 = fminf(px0 + 1.0f, 127.0f);
    float py1 = fminf(py0 + 1.0f, 127.0f);
    int ix0 = (int)px0, iy0 = (int)py0, ix1 = (int)px1, iy1 = (int)py1;
    float wy1 = __fsub_rn(py1, py), wy0 = __fsub_rn(py, py0);
    float wx1 = __fsub_rn(px1, px), wx0 = __fsub_rn(px, px0);
    soff[li][k][0] = (iy0 * WIDTH + ix0) * 128;
    soff[li][k][1] = (iy1 * WIDTH + ix0) * 128;
    soff[li][k][2] = (iy0 * WIDTH + ix1) * 128;
    soff[li][k][3] = (iy1 * WIDTH + ix1) * 128;
    swt[li][k][0] = __fmul_rn(wy1, wx1);   // wa -> r00
    swt[li][k][1] = __fmul_rn(wy0, wx1);   // wb -> r10
    swt[li][k][2] = __fmul_rn(wy1, wx0);   // wc -> r01
    swt[li][k][3] = __fmul_rn(wy0, wx0);   // wd -> r11
  }
  __syncthreads();
  int li = t >> 6, c2 = t & 63;            // channels 2*c2, 2*c2+1
  int l = l0 + blockIdx.x * 2 + li;
  const unsigned short* Lb = loi + (size_t)b * HW * 128 + (c2 << 1);
  float rm0 = -3.4e38f, rm1 = -3.4e38f;
  alignas(16) unsigned short outv[16];
#pragma unroll 4
  for (int k = 0; k < 32; ++k) {
    int4   o = *(const int4*)soff[li][k];
    float4 w = *(const float4*)swt[li][k];
    unsigned int u0 = *(const unsigned int*)(Lb + o.x);
    unsigned int u1 = *(const unsigned int*)(Lb + o.y);
    unsigned int u2 = *(const unsigned int*)(Lb + o.z);
    unsigned int u3 = *(const unsigned int*)(Lb + o.w);
    float2 v0 = bf2x2(u0), v1 = bf2x2(u1), v2 = bf2x2(u2), v3 = bf2x2(u3);
    float a0 = __fadd_rn(__fadd_rn(__fadd_rn(__fmul_rn(v0.x, w.x), __fmul_rn(v1.x, w.y)),
                                   __fmul_rn(v2.x, w.z)), __fmul_rn(v3.x, w.w));
    float a1 = __fadd_rn(__fadd_rn(__fadd_rn(__fmul_rn(v0.y, w.x), __fmul_rn(v1.y, w.y)),
                                   __fmul_rn(v2.y, w.z)), __fmul_rn(v3.y, w.w));
    rm0 = fmaxf(rm0, a0);
    rm1 = fmaxf(rm1, a1);
    if ((k & 3) == 3) {
      outv[k >> 2]       = f2bf(rm0);
      outv[8 + (k >> 2)] = f2bf(rm1);
      rm0 = -3.4e38f; rm1 = -3.4e38f;
    }
  }
  unsigned short* dst = xvec + (size_t)(l - l0) * 1024 + c2 * 16;
  *(s16x8*)dst       = *(const s16x8*)outv;
  *(s16x8*)(dst + 8) = *(const s16x8*)(outv + 8);
}

// ---------------------------------------------------------------- fc1: C = relu(A @ Bt^T + bias), bf16 out
// 128x128 tile, 4 waves, BK=32, double-buffered LDS (1 barrier/iter), LDS-staged epilogue.
__global__ __launch_bounds__(256) void k_fc1(const unsigned short* __restrict__ A,
                                             const unsigned short* __restrict__ Bt,
                                             const float* __restrict__ bias,
                                             unsigned short* __restrict__ C) {
  const int K = 1024, N = 1024;
  __shared__ short sm[17408];          // dbuf: [buf][A 4096 | B 4096]; epilogue: 128 x 136
  int t = threadIdx.x, lane = t & 63, w = t >> 6;
  int wm = w & 1, wn = w >> 1;
  int lr = lane & 15, ls = lane >> 4;
  int m0 = blockIdx.x * 128, n0 = blockIdx.y * 128;

  f32x4 acc[4][4];
#pragma unroll
  for (int i = 0; i < 4; ++i)
#pragma unroll
    for (int j = 0; j < 4; ++j) acc[i][j] = (f32x4){0.f, 0.f, 0.f, 0.f};

  const unsigned short* ga0 = A + (size_t)(m0 + w * 16 + lr) * K + ls * 8;
  const unsigned short* ga1 = A + (size_t)(m0 + (w + 4) * 16 + lr) * K + ls * 8;
  const unsigned short* gb0 = Bt + (size_t)(n0 + w * 16 + lr) * K + ls * 8;
  const unsigned short* gb1 = Bt + (size_t)(n0 + (w + 4) * 16 + lr) * K + ls * 8;

  GLOAD_LDS16(ga0, sm + w * 512);
  GLOAD_LDS16(ga1, sm + (w + 4) * 512);
  GLOAD_LDS16(gb0, sm + 4096 + w * 512);
  GLOAD_LDS16(gb1, sm + 4096 + (w + 4) * 512);
  __syncthreads();

  int cur = 0;
  for (int k0 = 0; k0 < K; k0 += 32) {
    int nxt = cur ^ 1;
    if (k0 + 32 < K) {
      int ko = k0 + 32;
      short* d = sm + nxt * 8192;
      GLOAD_LDS16(ga0 + ko, d + w * 512);
      GLOAD_LDS16(ga1 + ko, d + (w + 4) * 512);
      GLOAD_LDS16(gb0 + ko, d + 4096 + w * 512);
      GLOAD_LDS16(gb1 + ko, d + 4096 + (w + 4) * 512);
    }
    const short* As = sm + cur * 8192;
    const short* Bs = As + 4096;
    s16x8 af[4], bfr[4];
#pragma unroll
    for (int mi = 0; mi < 4; ++mi) af[mi] = *(const s16x8*)(As + (wm * 4 + mi) * 512 + lane * 8);
#pragma unroll
    for (int ni = 0; ni < 4; ++ni) bfr[ni] = *(const s16x8*)(Bs + (wn * 4 + ni) * 512 + lane * 8);
#pragma unroll
    for (int mi = 0; mi < 4; ++mi)
#pragma unroll
      for (int ni = 0; ni < 4; ++ni)
        acc[mi][ni] = __builtin_amdgcn_mfma_f32_16x16x32_bf16(af[mi], bfr[ni], acc[mi][ni], 0, 0, 0);
    __syncthreads();
    cur = nxt;
  }

  // epilogue: stage C tile in LDS (stride 136 shorts), then coalesced stores
#pragma unroll
  for (int ni = 0; ni < 4; ++ni) {
    int cl = wn * 64 + ni * 16 + lr;
    float bv = bias[n0 + cl];
#pragma unroll
    for (int mi = 0; mi < 4; ++mi) {
      int rl = wm * 64 + mi * 16 + ls * 4;
#pragma unroll
      for (int r = 0; r < 4; ++r)
        sm[(rl + r) * 136 + cl] = (short)f2bf(fmaxf(acc[mi][ni][r] + bv, 0.0f));
    }
  }
  __syncthreads();
  {
    int row = t >> 1, half = t & 1;
    const short* src = sm + row * 136 + half * 64;
    unsigned short* dst = C + (size_t)(m0 + row) * N + n0 + half * 64;
#pragma unroll
    for (int i = 0; i < 8; ++i)
      *(s16x8*)(dst + i * 8) = *(const s16x8*)(src + i * 8);
  }
}

// ---------------------------------------------------------------- fc2 fused with logits: atomicAdd partial dots
// logits[base+row] += sum_col relu(A@Bt^T + b2)[row][col] * w3[col]
__global__ __launch_bounds__(256) void k_fc2log(const unsigned short* __restrict__ A,
                                                const unsigned short* __restrict__ Bt,
                                                const float* __restrict__ bias,
                                                const float* __restrict__ w3,
                                                float* __restrict__ logits,
                                                int base) {
  const int K = 1024;
  __shared__ short sm[16384];
  int t = threadIdx.x, lane = t & 63, w = t >> 6;
  int wm = w & 1, wn = w >> 1;
  int lr = lane & 15, ls = lane >> 4;
  int m0 = blockIdx.x * 128, n0 = blockIdx.y * 128;

  f32x4 acc[4][4];
#pragma unroll
  for (int i = 0; i < 4; ++i)
#pragma unroll
    for (int j = 0; j < 4; ++j) acc[i][j] = (f32x4){0.f, 0.f, 0.f, 0.f};

  const unsigned short* ga0 = A + (size_t)(m0 + w * 16 + lr) * K + ls * 8;
  const unsigned short* ga1 = A + (size_t)(m0 + (w + 4) * 16 + lr) * K + ls * 8;
  const unsigned short* gb0 = Bt + (size_t)(n0 + w * 16 + lr) * K + ls * 8;
  const unsigned short* gb1 = Bt + (size_t)(n0 + (w + 4) * 16 + lr) * K + ls * 8;

  GLOAD_LDS16(ga0, sm + w * 512);
  GLOAD_LDS16(ga1, sm + (w + 4) * 512);
  GLOAD_LDS16(gb0, sm + 4096 + w * 512);
  GLOAD_LDS16(gb1, sm + 4096 + (w + 4) * 512);
  __syncthreads();

  int cur = 0;
  for (int k0 = 0; k0 < K; k0 += 32) {
    int nxt = cur ^ 1;
    if (k0 + 32 < K) {
      int ko = k0 + 32;
      short* d = sm + nxt * 8192;
      GLOAD_LDS16(ga0 + ko, d + w * 512);
      GLOAD_LDS16(ga1 + ko, d + (w + 4) * 512);
      GLOAD_LDS16(gb0 + ko, d + 4096 + w * 512);
      GLOAD_LDS16(gb1 + ko, d + 4096 + (w + 4) * 512);
    }
    const short* As = sm + cur * 8192;
    const short* Bs = As + 4096;
    s16x8 af[4], bfr[4];
#pragma unroll
    for (int mi = 0; mi < 4; ++mi) af[mi] = *(const s16x8*)(As + (wm * 4 + mi) * 512 + lane * 8);
#pragma unroll
    for (int ni = 0; ni < 4; ++ni) bfr[ni] = *(const s16x8*)(Bs + (wn * 4 + ni) * 512 + lane * 8);
#pragma unroll
    for (int mi = 0; mi < 4; ++mi)
#pragma unroll
      for (int ni = 0; ni < 4; ++ni)
        acc[mi][ni] = __builtin_amdgcn_mfma_f32_16x16x32_bf16(af[mi], bfr[ni], acc[mi][ni], 0, 0, 0);
    __syncthreads();
    cur = nxt;
  }

  // epilogue: psum[mi][r] = sum over this wave's 64 cols of relu(acc+b2)*w3
  float psum[4][4];
#pragma unroll
  for (int mi = 0; mi < 4; ++mi)
#pragma unroll
    for (int r = 0; r < 4; ++r) psum[mi][r] = 0.0f;
#pragma unroll
  for (int ni = 0; ni < 4; ++ni) {
    int col = n0 + wn * 64 + ni * 16 + lr;
    float bv = bias[col];
    float wv = w3[col];
#pragma unroll
    for (int mi = 0; mi < 4; ++mi)
#pragma unroll
      for (int r = 0; r < 4; ++r)
        psum[mi][r] += fmaxf(acc[mi][ni][r] + bv, 0.0f) * wv;
  }
#pragma unroll
  for (int mi = 0; mi < 4; ++mi)
#pragma unroll
    for (int r = 0; r < 4; ++r) {
      float v = psum[mi][r];
      v += __shfl_xor(v, 1, 64);
      v += __shfl_xor(v, 2, 64);
      v += __shfl_xor(v, 4, 64);
      v += __shfl_xor(v, 8, 64);
      if (lr == 0) {
        int row = m0 + wm * 64 + mi * 16 + ls * 4 + r;
        atomicAdd(&logits[base + row], v);
      }
    }
}

// ---------------------------------------------------------------- final: sigmoid + keep
__global__ __launch_bounds__(256) void k_fin(const float* __restrict__ logits,
                                             const float* __restrict__ b3,
                                             const int* __restrict__ iskeep,
                                             float* __restrict__ oscore,
                                             float* __restrict__ okeep,
                                             int base) {
  int gl = base + blockIdx.x * 256 + threadIdx.x;
  float sc = sigm(logits[gl] + b3[0]);
  oscore[gl] = sc;
  okeep[gl] = (iskeep[gl] && sc > 0.05f) ? 1.0f : 0.0f;
}

// ================================================================ host
extern "C" void kernel_launch(void* const* d_in, const int* in_sizes, int n_in,
                              void* d_out, int out_size, void* d_ws, size_t ws_size,
                              hipStream_t stream) {
  const float* output     = (const float*)d_in[0];
  const float* features   = (const float*)d_in[1];
  const float* line_preds = (const float*)d_in[2];
  const float* conv_w     = (const float*)d_in[3];
  const float* conv_b     = (const float*)d_in[4];
  const float* w1         = (const float*)d_in[5];
  const float* b1         = (const float*)d_in[6];
  const float* w2         = (const float*)d_in[7];
  const float* b2         = (const float*)d_in[8];
  const float* w3         = (const float*)d_in[9];
  const float* b3         = (const float*)d_in[10];

  char* ws = (char*)d_ws;
  size_t off = 0;
  auto alloc = [&](size_t bytes) -> void* {
    void* p = ws + off;
    off += (bytes + 255) & ~(size_t)255;
    return p;
  };
  float* wt      = (float*)alloc((size_t)256 * 128 * 4);
  unsigned short* loi = (unsigned short*)alloc((size_t)NB * HW * 128 * 2);
  float* jloc    = (float*)alloc((size_t)NB * HW * 4);
  unsigned long long* keys = (unsigned long long*)alloc((size_t)NB * HW * 8);
  float* jx      = (float*)alloc((size_t)NB * NTOPK * 4);
  float* jy      = (float*)alloc((size_t)NB * NTOPK * 4);
  float4* lines4 = (float4*)alloc((size_t)NB * HW * 16);
  int* iskeep    = (int*)alloc((size_t)NB * HW * 4);
  float* logits  = (float*)alloc((size_t)NB * HW * 4);
  unsigned short* w1b = (unsigned short*)alloc((size_t)1024 * 1024 * 2);   // [N][K] bf16
  unsigned short* w2b = (unsigned short*)alloc((size_t)1024 * 1024 * 2);
  size_t fixed = off;

  // pick activation size: merged (both images, M=32768) if it fits, else per-image chunks
  bool merged = (fixed + (size_t)2 * NB * HW * 1024 * 2 + 512 <= ws_size);
  int CH = 128;
  if (!merged) {
    const int cands[8] = {16384, 8192, 4096, 2048, 1024, 512, 256, 128};
    for (int ci = 0; ci < 8; ++ci) {
      if (fixed + (size_t)2 * cands[ci] * 1024 * 2 + 512 <= ws_size) { CH = cands[ci]; break; }
    }
  }
  size_t actrows = merged ? (size_t)NB * HW : (size_t)CH;
  unsigned short* xvec = (unsigned short*)alloc(actrows * 1024 * 2);
  unsigned short* h1   = (unsigned short*)alloc(actrows * 1024 * 2);

  float* out_lines  = (float*)d_out;              // (B, L, 2, 2)
  float* out_scores = out_lines + (size_t)NB * HW * 4;
  float* out_keep   = out_scores + (size_t)NB * HW;

  k_transpose_w<<<128, 256, 0, stream>>>(conv_w, wt);
  k_wtrans<<<dim3(32, 32), 256, 0, stream>>>(w1, w1b);
  k_wtrans<<<dim3(32, 32), 256, 0, stream>>>(w2, w2b);
  k_loi<<<dim3(HW / 64, NB), 256, 0, stream>>>(features, wt, conv_b, loi);
  k_jloc<<<NB * HW / 256, 256, 0, stream>>>(output, jloc);
  k_nmskey<<<NB * HW / 256, 256, 0, stream>>>(jloc, keys);
  k_topk<<<NB, 1024, 0, stream>>>(keys, output, jx, jy);
  k_lines<<<dim3(HW / 256, NB), 256, 0, stream>>>(line_preds, jx, jy, lines4, iskeep, out_lines, logits);

  if (merged) {
    for (int b = 0; b < NB; ++b)
      k_sample<<<HW / 2, 128, 0, stream>>>(loi, lines4, xvec + (size_t)b * HW * 1024, b, 0);
    int M = NB * HW;
    k_fc1<<<dim3(M / 128, 8), 256, 0, stream>>>(xvec, w1b, b1, h1);
    k_fc2log<<<dim3(M / 128, 8), 256, 0, stream>>>(h1, w2b, b2, w3, logits, 0);
    k_fin<<<M / 256, 256, 0, stream>>>(logits, b3, iskeep, out_scores, out_keep, 0);
  } else {
    int nchunk = HW / CH;
    for (int b = 0; b < NB; ++b) {
      for (int ci = 0; ci < nchunk; ++ci) {
        int l0 = ci * CH;
        int base = b * HW + l0;
        k_sample<<<CH / 2, 128, 0, stream>>>(loi, lines4, xvec, b, l0);
        k_fc1<<<dim3(CH / 128, 8), 256, 0, stream>>>(xvec, w1b, b1, h1);
        k_fc2log<<<dim3(CH / 128, 8), 256, 0, stream>>>(h1, w2b, b2, w3, logits, base);
        k_fin<<<CH / 256, 256, 0, stream>>>(logits, b3, iskeep, out_scores, out_keep, base);
      }
    }
  }
}